// Round 8
// baseline (79.911 us; speedup 1.0000x reference)
//
#include <hip/hip_runtime.h>

// IDW, POWER=2.0 -> w = 1/d2 (sqrt cancels). out = sum(w*v)/sum(w).
// B=2, P=131072, S=512.
// R8 = R7 with the compile fix: use clang ext_vector_type(4) instead of HIP
//     float4 for addrspace(4) loads (builtin vector type -> plain lvalue
//     conversion across address spaces; HIP_vector_type's ctor can't bind).
// Theory (unchanged): station data is wave-uniform -> read via addrspace(4)
//     "constant" pointers with uniform indices -> SMEM s_load into SGPRs.
//     Zero LDS + zero VALU cost for station traffic (R5/R6: LDS 15.4us was
//     fully serialized with VALU 14.9us). No LDS, no __syncthreads.
//     4-way rcp combine (1 v_rcp per 4 stations/point).
//     EPS2 folded into d2 fma chain (exact at d2==0: w -> 1/EPS^2 like ref).
// Floor: VALU ~14.9us (62 plain + 2 rcp per chunk/wave, 128 chunks, 2 w/SIMD).

#define BLOCK 256
#define GPT 2

typedef float v4f __attribute__((ext_vector_type(4)));
typedef const __attribute__((address_space(4))) v4f k_v4f;

__global__ __launch_bounds__(BLOCK) void idw_kernel(
    const float* __restrict__ station_coords,  // (B, S, 2)
    const float* __restrict__ station_values,  // (B, S)
    const float* __restrict__ grid_points,     // (B, P, 2)
    float* __restrict__ out,                   // (B, P)
    int P, int S) {

    const int b = blockIdx.y;

    // Wave-uniform station data through the scalar pipe:
    // coords: 2 stations per v4f (xA yA xB yB); values: 4 per v4f.
    k_v4f* sc4 = (k_v4f*)(station_coords + (size_t)b * S * 2);
    k_v4f* sv4 = (k_v4f*)(station_values + (size_t)b * S);

    // Thread handles points {2*tid, 2*tid+1}; grid sized exactly.
    const int tid = blockIdx.x * BLOCK + threadIdx.x;
    const float4 g01 = ((const float4*)grid_points)[(size_t)b * (P / 2) + tid];
    const float gx0 = g01.x, gy0 = g01.y, gx1 = g01.z, gy1 = g01.w;

    constexpr float EPS  = 1.1920928955078125e-07f;
    constexpr float EPS2 = EPS * EPS;

    float wsum0 = 0.0f, vsum0 = 0.0f;
    float wsum1 = 0.0f, vsum1 = 0.0f;

    // 4 stations (A,B,C,D) vs one point: 31 plain VALU + 1 rcp.
    // cAB = xA yA xB yB | cCD = xC yC xD yD | vv = vA vB vC vD (all SGPRs)
    auto quad = [&](float gx, float gy, float& ws, float& vs,
                    v4f cAB, v4f cCD, v4f vv) {
        const float dxa = gx - cAB.x, dya = gy - cAB.y;
        const float a = fmaf(dxa, dxa, fmaf(dya, dya, EPS2));
        const float dxb = gx - cAB.z, dyb = gy - cAB.w;
        const float bq = fmaf(dxb, dxb, fmaf(dyb, dyb, EPS2));
        const float dxc = gx - cCD.x, dyc = gy - cCD.y;
        const float c = fmaf(dxc, dxc, fmaf(dyc, dyc, EPS2));
        const float dxd = gx - cCD.z, dyd = gy - cCD.w;
        const float d = fmaf(dxd, dxd, fmaf(dyd, dyd, EPS2));
        const float pab = a * bq, pcd = c * d;
        const float sab = a + bq, scd = c + d;
        const float nab = fmaf(vv.y, a, vv.x * bq);  // vB*a + vA*b
        const float ncd = fmaf(vv.w, c, vv.z * d);   // vD*c + vC*d
        const float r = __builtin_amdgcn_rcpf(pab * pcd);
        ws = fmaf(fmaf(sab, pcd, scd * pab), r, ws);
        vs = fmaf(fmaf(nab, pcd, ncd * pab), r, vs);
    };

#pragma unroll 4
    for (int k = 0; k < 512 / 4; ++k) {
        const v4f cAB = sc4[2 * k + 0];   // s_load (uniform, constant AS)
        const v4f cCD = sc4[2 * k + 1];
        const v4f vv  = sv4[k];
        quad(gx0, gy0, wsum0, vsum0, cAB, cCD, vv);
        quad(gx1, gy1, wsum1, vsum1, cAB, cCD, vv);
    }

    const float r0 = vsum0 / wsum0;
    const float r1 = vsum1 / wsum1;
    ((float2*)out)[(size_t)b * (P / 2) + tid] = make_float2(r0, r1);
}

extern "C" void kernel_launch(void* const* d_in, const int* in_sizes, int n_in,
                              void* d_out, int out_size, void* d_ws, size_t ws_size,
                              hipStream_t stream) {
    const float* station_coords = (const float*)d_in[0];
    const float* station_values = (const float*)d_in[1];
    const float* grid_points    = (const float*)d_in[2];
    float* out = (float*)d_out;

    const int B = 2;
    const int S = in_sizes[1] / B;   // 512
    const int P = out_size / B;      // 131072

    dim3 grid(P / (BLOCK * GPT), B);  // 256 x 2 = 512 blocks, 2 per CU
    dim3 block(BLOCK);
    idw_kernel<<<grid, block, 0, stream>>>(station_coords, station_values,
                                           grid_points, out, P, S);
}